// Round 2
// baseline (114.375 us; speedup 1.0000x reference)
//
#include <hip/hip_runtime.h>

#define NPAIR  144
#define KLEN   512
#define GPTS   2048
#define NFRM   256
#define FPB    4                  // frames per gather block
#define NFG    (NFRM / FPB)       // 64 frame groups
#define GSPLIT 8                  // g splits per frame group
#define GPB    (GPTS / GSPLIT)    // 256 g per block (1 per thread)
#define NSLOT  16                 // staged lags: k in {0..7} U {504..511}
#define NJ4    (NPAIR / 4)        // 36 packed-index dwords per g
#define EPSV   1e-12f

// tau0 values are geometrically bounded: |lag| <= 0.1m*16000/343 = 4.66,
// so tau in {0..5} U {507..511}. slot = tau & 15 is collision-free on that
// set ({0..5} U {11..15}), so we stage only 16 slots (k 0..7 and 504..511):
// LDS halves to 36 KiB -> 2 blocks/CU, and staged global bytes halve.
// Bank-conflict swizzle: slot' = slot ^ (pair&7) (bits 0-2 only, stays
// within the 8-slot segment), pre-folded into the packed table.
// taub layout is g-major: taub[g*36 + j4], so each gather thread loads its
// 36 index dwords as 9 dwordx4.
__global__ void pack_tau_kernel(const int* __restrict__ tau0,
                                unsigned* __restrict__ taub) {
    int i = blockIdx.x * 256 + threadIdx.x;     // NJ4*GPTS = 73728
    if (i >= NJ4 * GPTS) return;
    int g  = i & (GPTS - 1);
    int j4 = i >> 11;
    unsigned d = 0;
    #pragma unroll
    for (int b = 0; b < 4; ++b) {
        int pair = j4 * 4 + b;
        int v = tau0[pair * GPTS + g];
        unsigned s = ((unsigned)v & 15u) ^ (unsigned)(pair & 7);
        d |= s << (8 * b);
    }
    taub[(size_t)g * NJ4 + j4] = d;
}

// 512 blocks = 64 frame-groups x 8 g-splits, 256 threads (1 g x 4 frames).
// 36 KiB LDS -> 2 blocks/CU: block B+1's staging overlaps block B's main
// loop, hiding the staging latency that was serial at 1 block/CU.
__global__ __launch_bounds__(256)
void srp_gather_kernel(const float* __restrict__ x,
                       const unsigned* __restrict__ taub,
                       float* __restrict__ maps) {
    __shared__ __align__(16) float xc[NPAIR * NSLOT * FPB];   // 36864 B

    const int bi = blockIdx.x;
    const int fg = bi >> 3;
    const int gs = bi & (GSPLIT - 1);
    const int t  = threadIdx.x;
    const int g  = gs * GPB + t;

    // Stage clumps: item = (pair, fr, seg), 1152 items x 32 B.
    // seg0: k=0..7 -> slots 0..7 ; seg1: k=504..511 -> slots 8..15.
    // Store banks: ((slot^sw)*4 + fr) & 31 covers all 32 banks across the
    // wave's (pair x fr) lanes, 2 lanes/bank (segs) = conflict-free.
    for (int i = t; i < NPAIR * FPB * 2; i += 256) {
        int pair = i >> 3;
        int fr   = (i >> 1) & 3;
        int seg  = i & 1;
        int sw   = pair & 7;
        const float* src = x + ((size_t)(fg * FPB + fr) * NPAIR + pair) * KLEN
                             + (seg ? 504 : 0);
        int base = pair * NSLOT + seg * 8;
        #pragma unroll
        for (int jj = 0; jj < 2; ++jj) {
            float4 v = ((const float4*)src)[jj];
            xc[(base + ((jj * 4 + 0) ^ sw)) * FPB + fr] = v.x;
            xc[(base + ((jj * 4 + 1) ^ sw)) * FPB + fr] = v.y;
            xc[(base + ((jj * 4 + 2) ^ sw)) * FPB + fr] = v.z;
            xc[(base + ((jj * 4 + 3) ^ sw)) * FPB + fr] = v.w;
        }
    }

    // Prefetch all 36 packed-index dwords (9 x dwordx4, g-major layout) so
    // the L2 latency hides under the staging stores + barrier wait.
    uint4 dj[9];
    const uint4* tb = (const uint4*)(taub + (size_t)g * NJ4);
    #pragma unroll
    for (int q = 0; q < 9; ++q) dj[q] = tb[q];

    __syncthreads();

    float4 acc = {0.f, 0.f, 0.f, 0.f};
    #pragma unroll
    for (int q = 0; q < 9; ++q) {
        unsigned dw[4] = {dj[q].x, dj[q].y, dj[q].z, dj[q].w};
        #pragma unroll
        for (int w = 0; w < 4; ++w) {
            unsigned d = dw[w];
            int j4 = q * 4 + w;
            #pragma unroll
            for (int b = 0; b < 4; ++b) {
                unsigned s = (d >> (8 * b)) & 0xffu;   // slot, pre-swizzled
                const float4 v =
                    *(const float4*)&xc[((j4 * 4 + b) * NSLOT + s) * FPB];
                acc.x += v.x; acc.y += v.y; acc.z += v.z; acc.w += v.w;
            }
        }
    }

    float* mp = maps + (size_t)(fg * FPB) * GPTS + g;
    mp[0 * GPTS] = acc.x;
    mp[1 * GPTS] = acc.y;
    mp[2 * GPTS] = acc.z;
    mp[3 * GPTS] = acc.w;
}

// One block per frame: zero-mean, then divide by max.
__global__ __launch_bounds__(256)
void srp_norm_kernel(const float* __restrict__ maps, float* __restrict__ out) {
    __shared__ float red[5];
    const int f = blockIdx.x;
    const int t = threadIdx.x;
    const float4* p = (const float4*)(maps + (size_t)f * GPTS);
    float4 s0 = p[t], s1 = p[t + 256];

    const int wave = t >> 6, lane = t & 63;

    float sm = s0.x + s0.y + s0.z + s0.w + s1.x + s1.y + s1.z + s1.w;
    #pragma unroll
    for (int off = 32; off > 0; off >>= 1) sm += __shfl_down(sm, off, 64);
    if (lane == 0) red[wave] = sm;
    __syncthreads();
    if (t == 0) red[4] = (red[0] + red[1] + red[2] + red[3]) * (1.0f / (float)GPTS);
    __syncthreads();
    const float mean = red[4];

    s0.x = s0.x - mean + EPSV; s0.y = s0.y - mean + EPSV;
    s0.z = s0.z - mean + EPSV; s0.w = s0.w - mean + EPSV;
    s1.x = s1.x - mean + EPSV; s1.y = s1.y - mean + EPSV;
    s1.z = s1.z - mean + EPSV; s1.w = s1.w - mean + EPSV;

    float mx = fmaxf(fmaxf(fmaxf(s0.x, s0.y), fmaxf(s0.z, s0.w)),
                     fmaxf(fmaxf(s1.x, s1.y), fmaxf(s1.z, s1.w)));
    #pragma unroll
    for (int off = 32; off > 0; off >>= 1) mx = fmaxf(mx, __shfl_down(mx, off, 64));
    __syncthreads();
    if (lane == 0) red[wave] = mx;
    __syncthreads();
    if (t == 0) red[4] = fmaxf(fmaxf(red[0], red[1]), fmaxf(red[2], red[3]));
    __syncthreads();
    const float inv = 1.0f / red[4];

    float4* o = (float4*)(out + (size_t)f * GPTS);
    o[t]       = make_float4(s0.x * inv, s0.y * inv, s0.z * inv, s0.w * inv);
    o[t + 256] = make_float4(s1.x * inv, s1.y * inv, s1.z * inv, s1.w * inv);
}

extern "C" void kernel_launch(void* const* d_in, const int* in_sizes, int n_in,
                              void* d_out, int out_size, void* d_ws, size_t ws_size,
                              hipStream_t stream) {
    const float* x    = (const float*)d_in[0];
    const int*   tau0 = (const int*)d_in[1];
    float* out = (float*)d_out;

    unsigned* taub = (unsigned*)d_ws;                    // 288 KiB
    float* maps = (float*)((char*)d_ws + (1 << 20));     // 2 MiB

    const int npack = NJ4 * GPTS;
    pack_tau_kernel<<<(npack + 255) / 256, 256, 0, stream>>>(tau0, taub);
    srp_gather_kernel<<<NFG * GSPLIT, 256, 0, stream>>>(x, taub, maps);
    srp_norm_kernel<<<NFRM, 256, 0, stream>>>(maps, out);
}

// Round 3
// 110.241 us; speedup vs baseline: 1.0375x; 1.0375x over previous
//
#include <hip/hip_runtime.h>

#define NPAIR  144
#define KLEN   512
#define GPTS   2048
#define NFRM   256
#define FPB    4                  // frames per gather block
#define NFG    (NFRM / FPB)       // 64 frame groups
#define GSPLIT 4                  // g splits per frame group
#define GPB    (GPTS / GSPLIT)    // 512 g per block (1 per thread)
#define NSLOT  16                 // staged lags: k in {0..7} U {504..511}
#define NJ4    (NPAIR / 4)        // 36 packed-index dwords per g
#define EPSV   1e-12f

// Fused gather: 256 blocks = 64 frame-groups x 4 g-splits, 512 threads
// (1 g x 4 frames each). LDS holds only the lag clumps:
// xc[pair][slot][frame] = 36 KiB.
//
// tau0 values are geometrically bounded: |lag| <= 0.1m*16000/343 = 4.66,
// so tau in {0..5} U {507..511}; slot = tau & 15 is collision-free on that
// set ({0..5} U {11..15}). We stage 16 slots: seg0 k=0..7 -> slots 0..7,
// seg1 k=504..511 -> slots 8..15 (k & 15 in both cases).
//
// The former pack kernel is fused in: during the staging phase (VMEM
// latency-bound, VALU idle) each thread reads its 144 tau0 values
// (tau0[pair*2048+g] is coalesced across the wave: lanes vary g) and
// packs 4 pairs' slots per dword into 36 register dwords. This removes a
// kernel launch + dependency bubble and the taub write/read round-trip.
__global__ __launch_bounds__(512)
void srp_gather_kernel(const float* __restrict__ x,
                       const int* __restrict__ tau0,
                       float* __restrict__ maps) {
    __shared__ __align__(16) float xc[NPAIR * NSLOT * FPB];   // 36864 B

    const int bi = blockIdx.x;
    const int fg = bi >> 2;
    const int gs = bi & (GSPLIT - 1);
    const int t  = threadIdx.x;
    const int g  = gs * GPB + t;

    // Stage clumps: item = (pair, fr, seg), 1152 items x 32 B, ~2.25/thread.
    for (int i = t; i < NPAIR * FPB * 2; i += 512) {
        int pair = i >> 3;
        int fr   = (i >> 1) & 3;
        int seg  = i & 1;
        const float* src = x + ((size_t)(fg * FPB + fr) * NPAIR + pair) * KLEN
                             + (seg ? 504 : 0);
        int base = pair * NSLOT + seg * 8;
        #pragma unroll
        for (int jj = 0; jj < 2; ++jj) {
            float4 v = ((const float4*)src)[jj];
            xc[(base + jj * 4 + 0) * FPB + fr] = v.x;
            xc[(base + jj * 4 + 1) * FPB + fr] = v.y;
            xc[(base + jj * 4 + 2) * FPB + fr] = v.z;
            xc[(base + jj * 4 + 3) * FPB + fr] = v.w;
        }
    }

    // In-register index pack (hidden under staging-load latency + barrier):
    // dj[j4] byte b = slot of pair (j4*4+b) for this thread's g.
    unsigned dj[NJ4];
    #pragma unroll
    for (int j4 = 0; j4 < NJ4; ++j4) {
        unsigned d = 0;
        #pragma unroll
        for (int b = 0; b < 4; ++b) {
            int v = tau0[(j4 * 4 + b) * GPTS + g];   // coalesced (lanes vary g)
            d |= ((unsigned)v & 15u) << (8 * b);
        }
        dj[j4] = d;
    }

    __syncthreads();

    float4 acc = {0.f, 0.f, 0.f, 0.f};
    #pragma unroll
    for (int j4 = 0; j4 < NJ4; ++j4) {
        unsigned d = dj[j4];
        #pragma unroll
        for (int b = 0; b < 4; ++b) {
            unsigned s = (d >> (8 * b)) & 0xffu;
            const float4 v = *(const float4*)&xc[((j4 * 4 + b) * NSLOT + s) * FPB];
            acc.x += v.x; acc.y += v.y; acc.z += v.z; acc.w += v.w;
        }
    }

    float* mp = maps + (size_t)(fg * FPB) * GPTS + g;
    mp[0 * GPTS] = acc.x;
    mp[1 * GPTS] = acc.y;
    mp[2 * GPTS] = acc.z;
    mp[3 * GPTS] = acc.w;
}

// One block per frame: zero-mean, then divide by max.
__global__ __launch_bounds__(256)
void srp_norm_kernel(const float* __restrict__ maps, float* __restrict__ out) {
    __shared__ float red[5];
    const int f = blockIdx.x;
    const int t = threadIdx.x;
    const float4* p = (const float4*)(maps + (size_t)f * GPTS);
    float4 s0 = p[t], s1 = p[t + 256];

    const int wave = t >> 6, lane = t & 63;

    float sm = s0.x + s0.y + s0.z + s0.w + s1.x + s1.y + s1.z + s1.w;
    #pragma unroll
    for (int off = 32; off > 0; off >>= 1) sm += __shfl_down(sm, off, 64);
    if (lane == 0) red[wave] = sm;
    __syncthreads();
    if (t == 0) red[4] = (red[0] + red[1] + red[2] + red[3]) * (1.0f / (float)GPTS);
    __syncthreads();
    const float mean = red[4];

    s0.x = s0.x - mean + EPSV; s0.y = s0.y - mean + EPSV;
    s0.z = s0.z - mean + EPSV; s0.w = s0.w - mean + EPSV;
    s1.x = s1.x - mean + EPSV; s1.y = s1.y - mean + EPSV;
    s1.z = s1.z - mean + EPSV; s1.w = s1.w - mean + EPSV;

    float mx = fmaxf(fmaxf(fmaxf(s0.x, s0.y), fmaxf(s0.z, s0.w)),
                     fmaxf(fmaxf(s1.x, s1.y), fmaxf(s1.z, s1.w)));
    #pragma unroll
    for (int off = 32; off > 0; off >>= 1) mx = fmaxf(mx, __shfl_down(mx, off, 64));
    __syncthreads();
    if (lane == 0) red[wave] = mx;
    __syncthreads();
    if (t == 0) red[4] = fmaxf(fmaxf(red[0], red[1]), fmaxf(red[2], red[3]));
    __syncthreads();
    const float inv = 1.0f / red[4];

    float4* o = (float4*)(out + (size_t)f * GPTS);
    o[t]       = make_float4(s0.x * inv, s0.y * inv, s0.z * inv, s0.w * inv);
    o[t + 256] = make_float4(s1.x * inv, s1.y * inv, s1.z * inv, s1.w * inv);
}

extern "C" void kernel_launch(void* const* d_in, const int* in_sizes, int n_in,
                              void* d_out, int out_size, void* d_ws, size_t ws_size,
                              hipStream_t stream) {
    const float* x    = (const float*)d_in[0];
    const int*   tau0 = (const int*)d_in[1];
    float* out = (float*)d_out;

    float* maps = (float*)d_ws;                          // 2 MiB

    srp_gather_kernel<<<NFG * GSPLIT, 512, 0, stream>>>(x, tau0, maps);
    srp_norm_kernel<<<NFRM, 256, 0, stream>>>(maps, out);
}

// Round 4
// 108.493 us; speedup vs baseline: 1.0542x; 1.0161x over previous
//
#include <hip/hip_runtime.h>

#define NPAIR  144
#define KLEN   512
#define GPTS   2048
#define NFRM   256
#define FPB    4                  // frames per gather block
#define NFG    (NFRM / FPB)       // 64 frame groups
#define GSPLIT 4                  // g splits per frame group
#define GPB    (GPTS / GSPLIT)    // 512 g per block (1 per thread)
#define NSLOT  16                 // staged lags: k in {0..7} U {504..511}
#define NJ4    (NPAIR / 4)        // 36 packed-index dwords per g
#define EPSV   1e-12f

// Fused gather: 256 blocks = 64 frame-groups x 4 g-splits, 512 threads
// (1 g x 4 frames each). LDS holds only the lag clumps:
// xc[pair][slot][frame] = 36 KiB.
//
// XCD-locality: blocks dispatch round-robin across the 8 XCDs (XCD = bi%8).
// Encoding fg = bi & 63, gs = bi >> 6 puts the 4 g-split siblings of each
// frame-group (which stage IDENTICAL x-clumps) at bi = fg + {0,64,128,192},
// all congruent mod 8 -> same XCD. Sibling 1 pulls the clump sectors from
// HBM; siblings 2-4 hit that XCD's L2 (~0.6 MB working set vs 4 MB L2).
// This cuts staging HBM traffic ~4x and staging latency ~900 -> ~200 cyc
// for 75% of loads, which is the serial pre-barrier critical path.
//
// tau0 values are geometrically bounded: |lag| <= 0.1m*16000/343 = 4.66,
// so tau in {0..5} U {507..511}; slot = tau & 15 is collision-free on that
// set ({0..5} U {11..15}). We stage 16 slots: seg0 k=0..7 -> slots 0..7,
// seg1 k=504..511 -> slots 8..15 (k & 15 in both cases).
//
// Index prep is fused: during the staging phase (VMEM latency-bound, VALU
// idle) each thread reads its 144 tau0 values (coalesced: lanes vary g)
// and packs 4 pairs' BYTE OFFSETS (slot*16, fits in a byte: max 240) per
// dword, so the gather address is one bfe+add.
__global__ __launch_bounds__(512)
void srp_gather_kernel(const float* __restrict__ x,
                       const int* __restrict__ tau0,
                       float* __restrict__ maps) {
    __shared__ __align__(16) float xc[NPAIR * NSLOT * FPB];   // 36864 B

    const int bi = blockIdx.x;
    const int fg = bi & (NFG - 1);          // XCD-locality encoding (see above)
    const int gs = bi >> 6;
    const int t  = threadIdx.x;
    const int g  = gs * GPB + t;

    // Stage clumps: item = (pair, fr, seg), 1152 items x 32 B, ~2.25/thread.
    for (int i = t; i < NPAIR * FPB * 2; i += 512) {
        int pair = i >> 3;
        int fr   = (i >> 1) & 3;
        int seg  = i & 1;
        const float* src = x + ((size_t)(fg * FPB + fr) * NPAIR + pair) * KLEN
                             + (seg ? 504 : 0);
        int base = pair * NSLOT + seg * 8;
        #pragma unroll
        for (int jj = 0; jj < 2; ++jj) {
            float4 v = ((const float4*)src)[jj];
            xc[(base + jj * 4 + 0) * FPB + fr] = v.x;
            xc[(base + jj * 4 + 1) * FPB + fr] = v.y;
            xc[(base + jj * 4 + 2) * FPB + fr] = v.z;
            xc[(base + jj * 4 + 3) * FPB + fr] = v.w;
        }
    }

    // In-register index pack (hidden under staging-load latency + barrier):
    // dj[j4] byte b = (slot << 4) = LDS byte offset within pair's clump row.
    unsigned dj[NJ4];
    #pragma unroll
    for (int j4 = 0; j4 < NJ4; ++j4) {
        unsigned d = 0;
        #pragma unroll
        for (int b = 0; b < 4; ++b) {
            int v = tau0[(j4 * 4 + b) * GPTS + g];   // coalesced (lanes vary g)
            d |= (((unsigned)v & 15u) << 4) << (8 * b);
        }
        dj[j4] = d;
    }

    __syncthreads();

    const char* xb = (const char*)xc;
    float4 acc = {0.f, 0.f, 0.f, 0.f};
    #pragma unroll
    for (int j4 = 0; j4 < NJ4; ++j4) {
        unsigned d = dj[j4];
        #pragma unroll
        for (int b = 0; b < 4; ++b) {
            // byte addr = pair*256 + slot*16 (pair row = 16 slots x 16 B)
            unsigned off = (d >> (8 * b)) & 0xf0u;
            const float4 v = *(const float4*)(xb + (((j4 * 4 + b) << 8) + off));
            acc.x += v.x; acc.y += v.y; acc.z += v.z; acc.w += v.w;
        }
    }

    float* mp = maps + (size_t)(fg * FPB) * GPTS + g;
    mp[0 * GPTS] = acc.x;
    mp[1 * GPTS] = acc.y;
    mp[2 * GPTS] = acc.z;
    mp[3 * GPTS] = acc.w;
}

// One block per frame: zero-mean, then divide by max.
__global__ __launch_bounds__(256)
void srp_norm_kernel(const float* __restrict__ maps, float* __restrict__ out) {
    __shared__ float red[5];
    const int f = blockIdx.x;
    const int t = threadIdx.x;
    const float4* p = (const float4*)(maps + (size_t)f * GPTS);
    float4 s0 = p[t], s1 = p[t + 256];

    const int wave = t >> 6, lane = t & 63;

    float sm = s0.x + s0.y + s0.z + s0.w + s1.x + s1.y + s1.z + s1.w;
    #pragma unroll
    for (int off = 32; off > 0; off >>= 1) sm += __shfl_down(sm, off, 64);
    if (lane == 0) red[wave] = sm;
    __syncthreads();
    if (t == 0) red[4] = (red[0] + red[1] + red[2] + red[3]) * (1.0f / (float)GPTS);
    __syncthreads();
    const float mean = red[4];

    s0.x = s0.x - mean + EPSV; s0.y = s0.y - mean + EPSV;
    s0.z = s0.z - mean + EPSV; s0.w = s0.w - mean + EPSV;
    s1.x = s1.x - mean + EPSV; s1.y = s1.y - mean + EPSV;
    s1.z = s1.z - mean + EPSV; s1.w = s1.w - mean + EPSV;

    float mx = fmaxf(fmaxf(fmaxf(s0.x, s0.y), fmaxf(s0.z, s0.w)),
                     fmaxf(fmaxf(s1.x, s1.y), fmaxf(s1.z, s1.w)));
    #pragma unroll
    for (int off = 32; off > 0; off >>= 1) mx = fmaxf(mx, __shfl_down(mx, off, 64));
    __syncthreads();
    if (lane == 0) red[wave] = mx;
    __syncthreads();
    if (t == 0) red[4] = fmaxf(fmaxf(red[0], red[1]), fmaxf(red[2], red[3]));
    __syncthreads();
    const float inv = 1.0f / red[4];

    float4* o = (float4*)(out + (size_t)f * GPTS);
    o[t]       = make_float4(s0.x * inv, s0.y * inv, s0.z * inv, s0.w * inv);
    o[t + 256] = make_float4(s1.x * inv, s1.y * inv, s1.z * inv, s1.w * inv);
}

extern "C" void kernel_launch(void* const* d_in, const int* in_sizes, int n_in,
                              void* d_out, int out_size, void* d_ws, size_t ws_size,
                              hipStream_t stream) {
    const float* x    = (const float*)d_in[0];
    const int*   tau0 = (const int*)d_in[1];
    float* out = (float*)d_out;

    float* maps = (float*)d_ws;                          // 2 MiB

    srp_gather_kernel<<<NFG * GSPLIT, 512, 0, stream>>>(x, tau0, maps);
    srp_norm_kernel<<<NFRM, 256, 0, stream>>>(maps, out);
}